// Round 9
// baseline (207.976 us; speedup 1.0000x reference)
//
#include <hip/hip_runtime.h>
#include <hip/hip_bf16.h>
#include <math.h>

#define NCLS 256
#define PER_CLASS 128
#define NSUP 5
#define NQRY 123              // PER_CLASS - NSUP
#define NVIEW 2
#define DD 384
#define NQ_TOT (NCLS * NQRY)  // 31488
#define NKT 12                // K tiles of 32
#define ASTR 40               // A LDS row stride in ushorts (32 data + 8 pad)

typedef __attribute__((ext_vector_type(8))) short short8;
typedef __attribute__((ext_vector_type(4))) float floatx4;

union FragU { uint4 u; short8 s; };
union PkU { __hip_bfloat162 b2; unsigned int u; };

__device__ __forceinline__ unsigned int cvt2bf(float lo, float hi) {
    PkU p;
    p.b2 = __float22bfloat162_rn(make_float2(lo, hi));
    return p.u;
}

// wave-local ordering for ds_write -> ds_read (NO s_barrier: waves stay decoupled)
#define WSYNC() asm volatile("s_waitcnt lgkmcnt(0)" ::: "memory")

// ---------- kernel 1: prototypes -> frag-ordered bf16 P + y2 ----------
// ppk layout (ushorts): [((v*12+kt)*16+nt)*512 + (quad*16+col)*8 + j]
//   = exactly the 16x16x32 B-fragment order: one contiguous 1 KB per (v,kt,nt),
//   lane (quad*16+col) holds P[class=nt*16+col][k=kt*32+quad*8+j].
__global__ __launch_bounds__(384) void proto_kernel(const float* __restrict__ reps,
                                                    ushort* __restrict__ ppk,
                                                    float* __restrict__ y2) {
    __shared__ float wp[6];
    const int b = blockIdx.x;          // v*256 + c
    const int c = b & 255, v = b >> 8;
    const int d = threadIdx.x;         // 0..383 (k index)
    const float* p = reps + ((size_t)(c * PER_CLASS) * NVIEW + v) * DD + d;
    float s = 0.f;
#pragma unroll
    for (int k = 0; k < NSUP; ++k) s += p[(size_t)k * NVIEW * DD];
    s *= 0.2f;
    __hip_bfloat16 h = __float2bfloat16(s);
    const int kt = d >> 5, quad = (d >> 3) & 3, j = d & 7;
    const int nt = c >> 4, col = c & 15;
    ppk[(size_t)(((v * NKT + kt) * 16 + nt) * 512) + (quad * 16 + col) * 8 + j] =
        *reinterpret_cast<ushort*>(&h);
    float q = s * s;
#pragma unroll
    for (int o = 1; o < 64; o <<= 1) q += __shfl_xor(q, o);
    if ((d & 63) == 0) wp[d >> 6] = q;
    __syncthreads();
    if (d == 0) y2[b] = wp[0] + wp[1] + wp[2] + wp[3] + wp[4] + wp[5];
}

// ---------- kernel 2: barrier-free per-wave MFMA GEMM + fused logsumexp/NLL ----------
// One 64-thread block == one wave; 32 queries x 256 classes; A via wave-private
// LDS (coalesced), B via coalesced frag-order global loads (L2-multicast).
__global__ __launch_bounds__(64, 2) void main_kernel(const float* __restrict__ reps,
                                                     const ushort* __restrict__ ppk,
                                                     const float* __restrict__ y2g,
                                                     float* __restrict__ out) {
    __shared__ ushort a_lds[2][32 * ASTR];  // 2 x 2560 B

    const int t = threadIdx.x;     // lane 0..63
    const int v = blockIdx.y;
    const int q0w = blockIdx.x * 32;
    const int col = t & 15;        // MFMA m/n index
    const int quad = t >> 4;       // MFMA k-oct / C row group

    // A staging: 2 lanes per query row (t>>1 = local row, (t&1)*16 = float offset)
    const int rr = q0w + (t >> 1);
    const float* qsrc = reps +
        (size_t)((rr / NQRY) * PER_CLASS + NSUP + (rr % NQRY)) * (NVIEW * DD) + v * DD + (t & 1) * 16;
    // B: frag-order stream, lane-contiguous
    const ushort* bsrc = ppk + ((size_t)v * NKT * 16) * 512 + t * 8;

    floatx4 acc[2][16];
#pragma unroll
    for (int m = 0; m < 2; ++m)
#pragma unroll
        for (int nt = 0; nt < 16; ++nt) acc[m][nt] = (floatx4)0.f;

    float4 qf[4];

#define ALOAD(kt)                                                      \
    do {                                                               \
        _Pragma("unroll") for (int i = 0; i < 4; ++i)                  \
            qf[i] = *(const float4*)(qsrc + (kt) * 32 + i * 4);        \
    } while (0)

#define ASTAGE(b)                                                      \
    do {                                                               \
        uint4 w0, w1;                                                  \
        w0.x = cvt2bf(qf[0].x, qf[0].y); w0.y = cvt2bf(qf[0].z, qf[0].w); \
        w0.z = cvt2bf(qf[1].x, qf[1].y); w0.w = cvt2bf(qf[1].z, qf[1].w); \
        w1.x = cvt2bf(qf[2].x, qf[2].y); w1.y = cvt2bf(qf[2].z, qf[2].w); \
        w1.z = cvt2bf(qf[3].x, qf[3].y); w1.w = cvt2bf(qf[3].z, qf[3].w); \
        *(uint4*)&a_lds[b][(t >> 1) * ASTR + (t & 1) * 16] = w0;       \
        *(uint4*)&a_lds[b][(t >> 1) * ASTR + (t & 1) * 16 + 8] = w1;   \
    } while (0)

    ALOAD(0);
    ASTAGE(0);
    ALOAD(1);
    WSYNC();

#pragma unroll
    for (int kt = 0; kt < NKT; ++kt) {
        // A fragments from wave-private LDS (rows col and col+16, k-oct quad*8)
        FragU A0, A1;
        A0.u = *(const uint4*)&a_lds[kt & 1][col * ASTR + quad * 8];
        A1.u = *(const uint4*)&a_lds[kt & 1][(col + 16) * ASTR + quad * 8];
        // rotate the A pipeline (no barrier: wave-local lgkm ordering only)
        if (kt < NKT - 1) {
            ASTAGE((kt + 1) & 1);
            if (kt < NKT - 2) ALOAD(kt + 2);
        }
        WSYNC();
        // B: 16 coalesced 1 KB frag loads + 32 MFMAs
#pragma unroll
        for (int nt = 0; nt < 16; ++nt) {
            FragU B;
            B.u = *(const uint4*)(bsrc + (size_t)(kt * 16 + nt) * 512);
            acc[0][nt] = __builtin_amdgcn_mfma_f32_16x16x32_bf16(A0.s, B.s, acc[0][nt], 0, 0, 0);
            acc[1][nt] = __builtin_amdgcn_mfma_f32_16x16x32_bf16(A1.s, B.s, acc[1][nt], 0, 0, 0);
        }
    }

    // ---- epilogue: wave-private logsumexp + NLL (verified in r7) ----
    float y2c[16];
#pragma unroll
    for (int nt = 0; nt < 16; ++nt) y2c[nt] = y2g[v * NCLS + nt * 16 + col];

    float corr = 0.f, lsum = 0.f;
#pragma unroll
    for (int m = 0; m < 2; ++m) {
#pragma unroll
        for (int r = 0; r < 4; ++r) {
            const int qn = q0w + m * 16 + quad * 4 + r;
            const int cn = qn / NQRY;
            float s[16];
            float mx = -1e30f;
#pragma unroll
            for (int nt = 0; nt < 16; ++nt) {
                s[nt] = 2.f * acc[m][nt][r] - y2c[nt];
                mx = fmaxf(mx, s[nt]);
                if (cn == nt * 16 + col) corr += s[nt];
            }
#pragma unroll
            for (int o = 1; o < 16; o <<= 1) mx = fmaxf(mx, __shfl_xor(mx, o));
            float e = 0.f;
#pragma unroll
            for (int nt = 0; nt < 16; ++nt) e += __expf(s[nt] - mx);
#pragma unroll
            for (int o = 1; o < 16; o <<= 1) e += __shfl_xor(e, o);
            if (col == 0) lsum += mx + __logf(e);
        }
    }
    float val = lsum - corr;
#pragma unroll
    for (int o = 1; o < 64; o <<= 1) val += __shfl_xor(val, o);
    if (t == 0) atomicAdd(out, val * (1.f / (float)(NQ_TOT * NVIEW)));
}

extern "C" void kernel_launch(void* const* d_in, const int* in_sizes, int n_in,
                              void* d_out, int out_size, void* d_ws, size_t ws_size,
                              hipStream_t stream) {
    const float* reps = (const float*)d_in[0];
    float* ws = (float*)d_ws;
    ushort* ppk = (ushort*)ws;                        // 2*12*16*512 = 196608 ushorts
    float* y2 = (float*)(ppk + NVIEW * NKT * 16 * 512);  // 512 floats
    float* out = (float*)d_out;

    hipMemsetAsync(out, 0, sizeof(float), stream);
    proto_kernel<<<dim3(NVIEW * NCLS), dim3(DD), 0, stream>>>(reps, ppk, y2);
    main_kernel<<<dim3(NQ_TOT / 32, NVIEW), dim3(64), 0, stream>>>(reps, ppk, y2, out);
}

// Round 10
// 196.467 us; speedup vs baseline: 1.0586x; 1.0586x over previous
//
#include <hip/hip_runtime.h>
#include <hip/hip_bf16.h>
#include <math.h>

#define NCLS 256
#define PER_CLASS 128
#define NSUP 5
#define NQRY 123              // PER_CLASS - NSUP
#define NVIEW 2
#define DD 384
#define NQ_TOT (NCLS * NQRY)  // 31488
#define BM 64                 // queries per block
#define BK 32                 // k-tile (elems)
#define NKT (DD / BK)         // 12
#define STR 40                // LDS row stride in ushorts (32 data + 8 pad; r2-proven)

typedef __attribute__((ext_vector_type(8))) short short8;
typedef __attribute__((ext_vector_type(4))) float floatx4;

union FragU { uint4 u; short8 s; };
union PkU { __hip_bfloat162 b2; unsigned int u; };

__device__ __forceinline__ unsigned int cvt2bf(float lo, float hi) {
    PkU p;
    p.b2 = __float22bfloat162_rn(make_float2(lo, hi));
    return p.u;
}

// barrier WITHOUT vmcnt(0) drain: LDS writes visible, global loads keep flying
#define BARRIER() asm volatile("s_waitcnt lgkmcnt(0)\n\ts_barrier" ::: "memory")

// ---------- kernel 1: prototypes -> per-k-tile-packed bf16 P + y2 ----------
// ppk layout (ushorts): [v][kt][c][32]  -> each (v,kt) tile is 16 KB contiguous;
// main_kernel thread t reads bytes [t*64, t*64+64) of a tile: fully coalesced.
__global__ __launch_bounds__(384) void proto_kernel(const float* __restrict__ reps,
                                                    ushort* __restrict__ ppk,
                                                    float* __restrict__ y2) {
    __shared__ float wp[6];
    const int b = blockIdx.x;          // v*256 + c
    const int c = b & 255, v = b >> 8;
    const int d = threadIdx.x;         // 0..383 (k index)
    const float* p = reps + ((size_t)(c * PER_CLASS) * NVIEW + v) * DD + d;
    float s = 0.f;
#pragma unroll
    for (int k = 0; k < NSUP; ++k) s += p[(size_t)k * NVIEW * DD];
    s *= 0.2f;
    __hip_bfloat16 h = __float2bfloat16(s);
    const int kt = d >> 5, kk = d & 31;
    ppk[(size_t)(((v * NKT + kt) * NCLS + c) * BK) + kk] = *reinterpret_cast<ushort*>(&h);
    float q = s * s;
#pragma unroll
    for (int o = 1; o < 64; o <<= 1) q += __shfl_xor(q, o);
    if ((d & 63) == 0) wp[d >> 6] = q;
    __syncthreads();
    if (d == 0) y2[b] = wp[0] + wp[1] + wp[2] + wp[3] + wp[4] + wp[5];
}

// ---------- kernel 2: bf16 MFMA GEMM (64q x 256c), 12 waves/CU, dist-2 pipeline ----------
__global__ __launch_bounds__(256, 3) void main_kernel(const float* __restrict__ reps,
                                                      const ushort* __restrict__ ppk,
                                                      const float* __restrict__ y2g,
                                                      float* __restrict__ out) {
    __shared__ ushort q_lds[2][BM * STR];    // 2 x 5120 B
    __shared__ ushort p_lds[2][NCLS * STR];  // 2 x 20480 B
    __shared__ float pmx[BM][2];
    __shared__ float pse[BM][2];
    __shared__ float cred[4];

    const int t = threadIdx.x;
    const int v = blockIdx.y;
    const int q0 = blockIdx.x * BM;
    const int wave = t >> 6;
    const int lane = t & 63;
    const int col = lane & 15;   // MFMA m/n index
    const int quad = lane >> 4;  // MFMA k-oct / C row group
    const int wm = wave >> 1;    // query half (32 rows)
    const int wn = wave & 1;     // class half (128 cols)

    // Q staging: 4 threads/row; t>>2 = row, (t&3)*8 = float offset (64 B segments)
    const int sq = t >> 2;
    const int qo = (t & 3) * 8;
    const int nq = q0 + sq;
    const float* qsrc = reps +
        (size_t)((nq / NQRY) * PER_CLASS + NSUP + (nq % NQRY)) * (NVIEW * DD) + v * DD + qo;
    ushort* qdst = &q_lds[0][0];  // buffer chosen per stage
    // P staging: thread t reads 64 contiguous bytes of the packed (v,kt) tile
    const ushort* psrc = ppk + (size_t)(v * NKT) * (NCLS * BK) + t * BK;

    floatx4 acc[2][8];
#pragma unroll
    for (int m = 0; m < 2; ++m)
#pragma unroll
        for (int nt = 0; nt < 8; ++nt) acc[m][nt] = (floatx4)0.f;

    float4 qf[2];
    uint4 pl[4];

#define LOADT(kt)                                                          \
    do {                                                                   \
        qf[0] = *(const float4*)(qsrc + (kt) * BK);                        \
        qf[1] = *(const float4*)(qsrc + (kt) * BK + 4);                    \
        _Pragma("unroll") for (int i = 0; i < 4; ++i)                      \
            pl[i] = *((const uint4*)(psrc + (size_t)(kt) * (NCLS * BK)) + i); \
    } while (0)

#define STAGE(b)                                                           \
    do {                                                                   \
        uint4 qw;                                                          \
        qw.x = cvt2bf(qf[0].x, qf[0].y); qw.y = cvt2bf(qf[0].z, qf[0].w);  \
        qw.z = cvt2bf(qf[1].x, qf[1].y); qw.w = cvt2bf(qf[1].z, qf[1].w);  \
        *(uint4*)&q_lds[b][sq * STR + qo] = qw;                            \
        _Pragma("unroll") for (int i = 0; i < 4; ++i)                      \
            *(uint4*)&p_lds[b][t * STR + i * 8] = pl[i];                   \
    } while (0)

#define COMPUTE(b)                                                         \
    do {                                                                   \
        short8 af[2];                                                      \
        _Pragma("unroll") for (int mt = 0; mt < 2; ++mt) {                 \
            FragU f;                                                       \
            f.u = *(const uint4*)&q_lds[b][(wm * 32 + mt * 16 + col) * STR + quad * 8]; \
            af[mt] = f.s;                                                  \
        }                                                                  \
        _Pragma("unroll") for (int nt = 0; nt < 8; ++nt) {                 \
            FragU bb;                                                      \
            bb.u = *(const uint4*)&p_lds[b][(wn * 128 + nt * 16 + col) * STR + quad * 8]; \
            _Pragma("unroll") for (int mt = 0; mt < 2; ++mt)               \
                acc[mt][nt] = __builtin_amdgcn_mfma_f32_16x16x32_bf16(af[mt], bb.s, acc[mt][nt], 0, 0, 0); \
        }                                                                  \
    } while (0)

    // ---- dist-2 pipelined K-loop (r6 pattern, lgkm-only barrier) ----
    LOADT(0);
    STAGE(0);
    LOADT(1);
    BARRIER();
#pragma unroll
    for (int kt = 0; kt < NKT; ++kt) {
        COMPUTE(kt & 1);
        if (kt < NKT - 1) {
            STAGE((kt + 1) & 1);       // vmcnt wait for tile kt+1 lands here
            if (kt < NKT - 2) LOADT(kt + 2);
            BARRIER();
        }
    }

    // ---- epilogue (r8-verified, BM=64) ----
    float y2c[8];
#pragma unroll
    for (int nt = 0; nt < 8; ++nt) y2c[nt] = y2g[v * NCLS + wn * 128 + nt * 16 + col];

    float corr = 0.f;
#pragma unroll
    for (int mt = 0; mt < 2; ++mt) {
#pragma unroll
        for (int r = 0; r < 4; ++r) {
            const int qloc = wm * 32 + mt * 16 + quad * 4 + r;
            const int n = q0 + qloc;
            const int cn = n / NQRY;
            float s[8];
            float mx = -1e30f;
#pragma unroll
            for (int nt = 0; nt < 8; ++nt) {
                s[nt] = 2.f * acc[mt][nt][r] - y2c[nt];
                mx = fmaxf(mx, s[nt]);
                if (cn == wn * 128 + nt * 16 + col) corr += s[nt];
            }
#pragma unroll
            for (int o = 1; o < 16; o <<= 1) mx = fmaxf(mx, __shfl_xor(mx, o));
            float e = 0.f;
#pragma unroll
            for (int nt = 0; nt < 8; ++nt) e += __expf(s[nt] - mx);
#pragma unroll
            for (int o = 1; o < 16; o <<= 1) e += __shfl_xor(e, o);
            if (col == 0) { pmx[qloc][wn] = mx; pse[qloc][wn] = e; }
        }
    }
#pragma unroll
    for (int o = 1; o < 64; o <<= 1) corr += __shfl_xor(corr, o);
    if (lane == 0) cred[wave] = corr;
    __syncthreads();

    float lval = 0.f;
    if (t < BM) {
        float m0 = pmx[t][0], m1 = pmx[t][1];
        float M = fmaxf(m0, m1);
        float E = pse[t][0] * __expf(m0 - M) + pse[t][1] * __expf(m1 - M);
        lval = M + __logf(E);
    }
#pragma unroll
    for (int o = 1; o < 64; o <<= 1) lval += __shfl_xor(lval, o);
    if (t == 0) {
        float tot = lval - (cred[0] + cred[1] + cred[2] + cred[3]);
        atomicAdd(out, tot * (1.f / (float)(NQ_TOT * NVIEW)));
    }
}

extern "C" void kernel_launch(void* const* d_in, const int* in_sizes, int n_in,
                              void* d_out, int out_size, void* d_ws, size_t ws_size,
                              hipStream_t stream) {
    const float* reps = (const float*)d_in[0];
    float* ws = (float*)d_ws;
    ushort* ppk = (ushort*)ws;                            // 2*12*256*32 = 196608 ushorts
    float* y2 = (float*)(ppk + NVIEW * NKT * NCLS * BK);  // 512 floats
    float* out = (float*)d_out;

    hipMemsetAsync(out, 0, sizeof(float), stream);
    proto_kernel<<<dim3(NVIEW * NCLS), dim3(DD), 0, stream>>>(reps, ppk, y2);
    main_kernel<<<dim3(NQ_TOT / BM, NVIEW), dim3(256), 0, stream>>>(reps, ppk, y2, out);
}